// Round 8
// baseline (633.650 us; speedup 1.0000x reference)
//
#include <hip/hip_runtime.h>
#include <math.h>

#define NN 100000
#define EE 1600000
#define ETOT (EE + NN)
#define NBUK 512
#define NPB 196        // nodes per bucket (512*196 >= NN)
#define CHUNK 3125     // 512*3125 == EE
#define CAP 6144       // LDS stage capacity per bucket (mean ~3332, +50 sigma)
#define CB 512         // chain blocks (blockIdx 0..511)
#define GB 1563        // gemm blocks: ceil(NN/64)

typedef __attribute__((ext_vector_type(8))) short bf16x8;
typedef __attribute__((ext_vector_type(4))) float f32x4;

__device__ __forceinline__ unsigned short f2bf(float f) {
  unsigned int u = __float_as_uint(f);
  u = u + 0x7fffu + ((u >> 16) & 1u);  // RNE
  return (unsigned short)(u >> 16);
}

__device__ __forceinline__ float lrelu_exp(float e) {
  e = (e > 0.f) ? e : 0.2f * e;
  return __expf(e);
}

// device-scope block barrier primitives (chain blocks only; GEMM blocks never wait)
__device__ __forceinline__ void arrive_cnt(int* c) {
  __threadfence();          // release: flush this block's global writes (per wave)
  __syncthreads();          // all waves' fences complete before publish
  if (threadIdx.x == 0)
    __hip_atomic_fetch_add(c, 1, __ATOMIC_RELAXED, __HIP_MEMORY_SCOPE_AGENT);
}
__device__ __forceinline__ void wait_cnt(int* c, int target) {
  if (threadIdx.x == 0) {
    while (__hip_atomic_load(c, __ATOMIC_RELAXED, __HIP_MEMORY_SCOPE_AGENT) < target)
      __builtin_amdgcn_s_sleep(2);
  }
  __syncthreads();
  __threadfence();          // acquire: invalidate caches before reading produced data
}

// ONE dispatch for everything before k_agg.
// blocks [0,CB): CSR chain p1 -> s1 -> s2 -> p3 -> p4 via spin barriers.
// blocks [CB, CB+GB): MFMA bf16 GEMM + fused logits (independent, concurrent).
// Chain LDS scratch overlays the GEMM's Wt buffer (union, not sum).
__global__ __launch_bounds__(256) void k_mega(const float* __restrict__ x,
                                              const float* __restrict__ W,
                                              const float* __restrict__ att_src,
                                              const float* __restrict__ att_dst,
                                              const int* __restrict__ ei,
                                              unsigned short* __restrict__ xwb,
                                              float* __restrict__ asrc,
                                              float* __restrict__ adst,
                                              int* __restrict__ H, int* __restrict__ R,
                                              int* __restrict__ T,
                                              int* __restrict__ BaseTmp,
                                              int* __restrict__ Base,
                                              int* __restrict__ tmpb,
                                              int* __restrict__ es, int* __restrict__ offs,
                                              int* __restrict__ sync) {
  __shared__ __align__(16) unsigned short lds[17408];  // GEMM: Wt[128][136]; chain: int scratch
  __shared__ float satt[256];
  int tid = threadIdx.x;
  int* ish = (int*)lds;  // 8704 ints of chain scratch

  if (blockIdx.x < CB) {
    int j = blockIdx.x;  // chunk id == bucket id
    // ---- P1: per-(chunk,bucket) histogram ----
    for (int i = tid; i < NBUK; i += 256) ish[i] = 0;
    __syncthreads();
    int e0 = j * CHUNK;
    for (int e = e0 + tid; e < e0 + CHUNK; e += 256) {
      int d = ei[(size_t)EE + e];
      atomicAdd(&ish[d / NPB], 1);
    }
    __syncthreads();
    for (int i = tid; i < NBUK; i += 256) H[j * NBUK + i] = ish[i];
    arrive_cnt(&sync[0]);
    wait_cnt(&sync[0], CB);

    // ---- S1: bucket j, exclusive scan over 512 chunk counts (2x256 halves) ----
    {
      int* s = ish;
      int va = H[tid * NBUK + j];
      int vb = H[(tid + 256) * NBUK + j];
      s[tid] = va;
      __syncthreads();
      for (int off = 1; off < 256; off <<= 1) {
        int tmp = (tid >= off) ? s[tid - off] : 0;
        __syncthreads();
        s[tid] += tmp;
        __syncthreads();
      }
      int Sa = s[tid], SaT = s[255];
      __syncthreads();
      s[tid] = vb;
      __syncthreads();
      for (int off = 1; off < 256; off <<= 1) {
        int tmp = (tid >= off) ? s[tid - off] : 0;
        __syncthreads();
        s[tid] += tmp;
        __syncthreads();
      }
      int Sb = s[tid];
      R[j * 512 + tid] = Sa - va;
      R[j * 512 + 256 + tid] = SaT + Sb - vb;
      if (tid == 255) T[j] = SaT + Sb;
    }
    arrive_cnt(&sync[1]);

    // ---- S2: block 0 only — bucket bases (two exclusive scans of 512) ----
    if (j == 0) {
      wait_cnt(&sync[1], CB);
      int* s = ish;
      int e2 = tid + 256;
      int v1 = T[tid], v2 = T[e2];
      int nc1 = NN - tid * NPB; nc1 = nc1 < 0 ? 0 : (nc1 > NPB ? NPB : nc1);
      int nc2 = NN - e2 * NPB;  nc2 = nc2 < 0 ? 0 : (nc2 > NPB ? NPB : nc2);
      int w1 = v1 + nc1, w2 = v2 + nc2;
      // scan v -> BaseTmp
      s[tid] = v1;
      __syncthreads();
      for (int off = 1; off < 256; off <<= 1) {
        int tmp = (tid >= off) ? s[tid - off] : 0;
        __syncthreads();
        s[tid] += tmp;
        __syncthreads();
      }
      int Sa = s[tid], SaT = s[255];
      __syncthreads();
      s[tid] = v2;
      __syncthreads();
      for (int off = 1; off < 256; off <<= 1) {
        int tmp = (tid >= off) ? s[tid - off] : 0;
        __syncthreads();
        s[tid] += tmp;
        __syncthreads();
      }
      BaseTmp[tid] = Sa - v1;
      BaseTmp[e2] = SaT + s[tid] - v2;
      __syncthreads();
      // scan w -> Base
      s[tid] = w1;
      __syncthreads();
      for (int off = 1; off < 256; off <<= 1) {
        int tmp = (tid >= off) ? s[tid - off] : 0;
        __syncthreads();
        s[tid] += tmp;
        __syncthreads();
      }
      int Sc = s[tid], ScT = s[255];
      __syncthreads();
      s[tid] = w2;
      __syncthreads();
      for (int off = 1; off < 256; off <<= 1) {
        int tmp = (tid >= off) ? s[tid - off] : 0;
        __syncthreads();
        s[tid] += tmp;
        __syncthreads();
      }
      Base[tid] = Sc - w1;
      Base[e2] = ScT + s[tid] - w2;
      arrive_cnt(&sync[2]);
    }
    wait_cnt(&sync[2], 1);

    // ---- P3: chunk j — deterministic partition by bucket ----
    {
      int* cur = ish;
      for (int b2 = tid; b2 < NBUK; b2 += 256) cur[b2] = BaseTmp[b2] + R[b2 * 512 + j];
      __syncthreads();
      for (int e = e0 + tid; e < e0 + CHUNK; e += 256) {
        int sv = ei[e];
        int dv = ei[(size_t)EE + e];
        int b2 = dv / NPB;
        int li = dv - b2 * NPB;
        int pos = atomicAdd(&cur[b2], 1);
        tmpb[pos] = (li << 17) | sv;
      }
    }
    arrive_cnt(&sync[3]);
    wait_cnt(&sync[3], CB);

    // ---- P4: bucket j — per-node count/scan/scatter in LDS, coalesced es ----
    {
      int* cnt = ish;          // 256
      int* curn = ish + 256;   // 196
      int* stage = ish + 512;  // 6144
      if (j == 0 && tid == 0) offs[NN] = ETOT;
      int n0 = j * NPB;
      int nloc = NN - n0;
      if (nloc > 0) {
        if (nloc > NPB) nloc = NPB;
        int total = T[j];
        int bt = BaseTmp[j], bs = Base[j];
        cnt[tid] = (tid < nloc) ? 1 : 0;  // self-loop pre-counted
        __syncthreads();
        for (int e = tid; e < total; e += 256) {
          int u = tmpb[bt + e];
          atomicAdd(&cnt[u >> 17], 1);
        }
        __syncthreads();
        int v = cnt[tid];
        __syncthreads();
        for (int off = 1; off < 256; off <<= 1) {
          int tmp = (tid >= off) ? cnt[tid - off] : 0;
          __syncthreads();
          cnt[tid] += tmp;
          __syncthreads();
        }
        int excl = cnt[tid] - v;
        if (tid < nloc) {
          offs[n0 + tid] = bs + excl;
          curn[tid] = excl + 1;
          if (excl < CAP) stage[excl] = n0 + tid;  // self-loop src first
        }
        __syncthreads();
        for (int e = tid; e < total; e += 256) {
          int u = tmpb[bt + e];
          int pos = atomicAdd(&curn[u >> 17], 1);
          if (pos < CAP) stage[pos] = u & 0x1FFFF;
        }
        __syncthreads();
        int btot = total + nloc;
        if (btot > CAP) btot = CAP;
        for (int i = tid; i < btot; i += 256) es[bs + i] = stage[i];
      }
    }
    return;
  }

  // ---- GEMM role ----
  int gb = blockIdx.x - CB;
  for (int i = tid; i < 16384; i += 256) {
    int k = i >> 7, n = i & 127;
    lds[n * 136 + k] = f2bf(W[i]);
  }
  if (tid < 128) satt[tid] = att_src[tid];
  else satt[tid] = att_dst[tid - 128];
  __syncthreads();

  int wv = tid >> 6, lane = tid & 63;
  int m = lane & 15, q = lane >> 4;
  int r = gb * 64 + wv * 16 + m;
  bool rok = (r < NN);

  bf16x8 af[4];
#pragma unroll
  for (int kt = 0; kt < 4; kt++) {
    float4 v0 = make_float4(0.f, 0.f, 0.f, 0.f), v1 = v0;
    if (rok) {
      v0 = ((const float4*)x)[(size_t)r * 32 + kt * 8 + q * 2];
      v1 = ((const float4*)x)[(size_t)r * 32 + kt * 8 + q * 2 + 1];
    }
    af[kt][0] = (short)f2bf(v0.x); af[kt][1] = (short)f2bf(v0.y);
    af[kt][2] = (short)f2bf(v0.z); af[kt][3] = (short)f2bf(v0.w);
    af[kt][4] = (short)f2bf(v1.x); af[kt][5] = (short)f2bf(v1.y);
    af[kt][6] = (short)f2bf(v1.z); af[kt][7] = (short)f2bf(v1.w);
  }

  f32x4 acc[8];
#pragma unroll
  for (int nt = 0; nt < 8; nt++) acc[nt] = (f32x4){0.f, 0.f, 0.f, 0.f};

#pragma unroll
  for (int nt = 0; nt < 8; nt++) {
#pragma unroll
    for (int kt = 0; kt < 4; kt++) {
      bf16x8 bf = *((const bf16x8*)&lds[(nt * 16 + m) * 136 + kt * 32 + q * 8]);
      acc[nt] = __builtin_amdgcn_mfma_f32_16x16x32_bf16(af[kt], bf, acc[nt], 0, 0, 0);
    }
  }

  __syncthreads();  // reuse LDS as output stage
#pragma unroll
  for (int nt = 0; nt < 8; nt++)
#pragma unroll
    for (int rg = 0; rg < 4; rg++)
      lds[(wv * 16 + q * 4 + rg) * 128 + nt * 16 + m] = f2bf(acc[nt][rg]);
  __syncthreads();

  size_t base = (size_t)gb * 16384;
  const size_t lim = (size_t)NN * 256;
  for (int i = tid; i < 1024; i += 256) {
    size_t off = base + (size_t)i * 16;
    if (off < lim) *((uint4*)((char*)xwb + off)) = ((const uint4*)lds)[i];
  }

  int row = tid >> 2, h = tid & 3;
  int node = gb * 64 + row;
  if (node < NN) {
    float ss = 0.f, sd = 0.f;
#pragma unroll
    for (int cq = 0; cq < 4; cq++) {
      uint4 u = *((const uint4*)&lds[row * 128 + h * 32 + cq * 8]);
      int cb = h * 32 + cq * 8;
      float f0 = __uint_as_float(u.x << 16), f1 = __uint_as_float(u.x & 0xffff0000u);
      float f2 = __uint_as_float(u.y << 16), f3 = __uint_as_float(u.y & 0xffff0000u);
      float f4 = __uint_as_float(u.z << 16), f5 = __uint_as_float(u.z & 0xffff0000u);
      float f6 = __uint_as_float(u.w << 16), f7 = __uint_as_float(u.w & 0xffff0000u);
      ss += f0 * satt[cb] + f1 * satt[cb + 1] + f2 * satt[cb + 2] + f3 * satt[cb + 3] +
            f4 * satt[cb + 4] + f5 * satt[cb + 5] + f6 * satt[cb + 6] + f7 * satt[cb + 7];
      sd += f0 * satt[128 + cb] + f1 * satt[128 + cb + 1] + f2 * satt[128 + cb + 2] +
            f3 * satt[128 + cb + 3] + f4 * satt[128 + cb + 4] + f5 * satt[128 + cb + 5] +
            f6 * satt[128 + cb + 6] + f7 * satt[128 + cb + 7];
    }
    asrc[(size_t)node * 4 + h] = ss;
    adst[(size_t)node * 4 + h] = sd;
  }
}

// one wave per destination node (unchanged from round 7 — masked final batch,
// es prefetch, register 8-way exp-duty select, in-register denominator).
__global__ __launch_bounds__(256) void k_agg(const unsigned short* __restrict__ xwb,
                                             const float* __restrict__ asrc,
                                             const float* __restrict__ adst,
                                             const int* __restrict__ offs,
                                             const int* __restrict__ es,
                                             const float* __restrict__ bias,
                                             const float* __restrict__ gamma,
                                             const float* __restrict__ beta,
                                             float* __restrict__ out) {
  int lane = threadIdx.x & 63;
  int node = blockIdx.x * 4 + (threadIdx.x >> 6);
  int off0 = offs[node];
  int d = offs[node + 1] - off0;
  int h = lane >> 4;
  int he = lane & 3;
  int sel = lane >> 3;
  int c = lane * 2;

  float4 ad4 = *((const float4*)(adst + (size_t)node * 4));
  float ade = (he & 2) ? ((he & 1) ? ad4.w : ad4.z) : ((he & 1) ? ad4.y : ad4.x);

  const unsigned* xp = (const unsigned*)xwb + lane;
  const int* ep = es + off0;
  float ax0 = 0.f, ay0 = 0.f, ax1 = 0.f, ay1 = 0.f;
  float wsum = 0.f;

  int nb = (d + 7) >> 3;
  int4 sa = *((const int4*)(ep));
  int4 sb = *((const int4*)(ep + 4));

  for (int b = 0; b < nb; ++b) {
    int4 na = *((const int4*)(ep + (b + 1) * 8));
    int4 nbv = *((const int4*)(ep + (b + 1) * 8 + 4));

    int base = b * 8;
    int s0 = sa.x, s1 = sa.y, s2 = sa.z, s3 = sa.w;
    int s4 = sb.x, s5 = sb.y, s6 = sb.z, s7 = sb.w;
    bool full = (base + 8 <= d);
    if (!full) {
      s0 = (base + 0 < d) ? s0 : 0; s1 = (base + 1 < d) ? s1 : 0;
      s2 = (base + 2 < d) ? s2 : 0; s3 = (base + 3 < d) ? s3 : 0;
      s4 = (base + 4 < d) ? s4 : 0; s5 = (base + 5 < d) ? s5 : 0;
      s6 = (base + 6 < d) ? s6 : 0; s7 = (base + 7 < d) ? s7 : 0;
    }
    int t0 = (sel & 1) ? s1 : s0;
    int t1 = (sel & 1) ? s3 : s2;
    int t2 = (sel & 1) ? s5 : s4;
    int t3 = (sel & 1) ? s7 : s6;
    int p0 = (sel & 2) ? t1 : t0;
    int p1 = (sel & 2) ? t3 : t2;
    int se = (sel & 4) ? p1 : p0;
    float av = asrc[(size_t)(unsigned)se * 4u + (unsigned)he];

    unsigned u0 = xp[(unsigned)s0 * 64u];
    unsigned u1 = xp[(unsigned)s1 * 64u];
    unsigned u2 = xp[(unsigned)s2 * 64u];
    unsigned u3 = xp[(unsigned)s3 * 64u];
    unsigned u4 = xp[(unsigned)s4 * 64u];
    unsigned u5 = xp[(unsigned)s5 * 64u];
    unsigned u6 = xp[(unsigned)s6 * 64u];
    unsigned u7 = xp[(unsigned)s7 * 64u];

    float wl = lrelu_exp(av + ade);
    float w0 = __shfl(wl, 0 * 8 + h);
    float w1 = __shfl(wl, 1 * 8 + h);
    float w2 = __shfl(wl, 2 * 8 + h);
    float w3 = __shfl(wl, 3 * 8 + h);
    float w4 = __shfl(wl, 4 * 8 + h);
    float w5 = __shfl(wl, 5 * 8 + h);
    float w6 = __shfl(wl, 6 * 8 + h);
    float w7 = __shfl(wl, 7 * 8 + h);
    if (!full) {
      w0 = (base + 0 < d) ? w0 : 0.f; w1 = (base + 1 < d) ? w1 : 0.f;
      w2 = (base + 2 < d) ? w2 : 0.f; w3 = (base + 3 < d) ? w3 : 0.f;
      w4 = (base + 4 < d) ? w4 : 0.f; w5 = (base + 5 < d) ? w5 : 0.f;
      w6 = (base + 6 < d) ? w6 : 0.f; w7 = (base + 7 < d) ? w7 : 0.f;
    }
    wsum += ((w0 + w1) + (w2 + w3)) + ((w4 + w5) + (w6 + w7));
    ax0 = fmaf(w0, __uint_as_float(u0 << 16), ax0);
    ay0 = fmaf(w0, __uint_as_float(u0 & 0xffff0000u), ay0);
    ax1 = fmaf(w1, __uint_as_float(u1 << 16), ax1);
    ay1 = fmaf(w1, __uint_as_float(u1 & 0xffff0000u), ay1);
    ax0 = fmaf(w2, __uint_as_float(u2 << 16), ax0);
    ay0 = fmaf(w2, __uint_as_float(u2 & 0xffff0000u), ay0);
    ax1 = fmaf(w3, __uint_as_float(u3 << 16), ax1);
    ay1 = fmaf(w3, __uint_as_float(u3 & 0xffff0000u), ay1);
    ax0 = fmaf(w4, __uint_as_float(u4 << 16), ax0);
    ay0 = fmaf(w4, __uint_as_float(u4 & 0xffff0000u), ay0);
    ax1 = fmaf(w5, __uint_as_float(u5 << 16), ax1);
    ay1 = fmaf(w5, __uint_as_float(u5 & 0xffff0000u), ay1);
    ax0 = fmaf(w6, __uint_as_float(u6 << 16), ax0);
    ay0 = fmaf(w6, __uint_as_float(u6 & 0xffff0000u), ay0);
    ax1 = fmaf(w7, __uint_as_float(u7 << 16), ax1);
    ay1 = fmaf(w7, __uint_as_float(u7 & 0xffff0000u), ay1);

    sa = na; sb = nbv;
  }

  float accx = ax0 + ax1, accy = ay0 + ay1;
  float rn = 1.f / (wsum + 1e-16f);

  float vx = accx * rn + bias[c];
  float vy = accy * rn + bias[c + 1];
  float sum = vx + vy, sq = vx * vx + vy * vy;
#pragma unroll
  for (int o = 32; o; o >>= 1) {
    sum += __shfl_xor(sum, o);
    sq += __shfl_xor(sq, o);
  }
  float mean = sum * (1.f / 128.f);
  float var = sq * (1.f / 128.f) - mean * mean;
  float rs = rsqrtf(var + 1e-5f);
  float o0 = gamma[c] * (vx - mean) * rs + beta[c];
  float o1 = gamma[c + 1] * (vy - mean) * rs + beta[c + 1];
  float2 ov; ov.x = o0; ov.y = o1;
  *((float2*)(out + (size_t)node * 128 + c)) = ov;
}

extern "C" void kernel_launch(void* const* d_in, const int* in_sizes, int n_in,
                              void* d_out, int out_size, void* d_ws, size_t ws_size,
                              hipStream_t stream) {
  const float* x = (const float*)d_in[0];
  const int* ei = (const int*)d_in[1];  // int32 per harness contract
  const float* W = (const float*)d_in[3];
  const float* att_src = (const float*)d_in[4];
  const float* att_dst = (const float*)d_in[5];
  const float* bias = (const float*)d_in[6];
  const float* gamma = (const float*)d_in[7];
  const float* beta = (const float*)d_in[8];
  float* out = (float*)d_out;

  char* p = (char*)d_ws;
  auto alloc = [&](size_t bytes) -> char* {
    char* r = p;
    p += (bytes + 255) & ~(size_t)255;
    return r;
  };
  unsigned short* xwb = (unsigned short*)alloc((size_t)NN * 128 * 2);  // 25.6 MB
  float* asrc = (float*)alloc((size_t)NN * 4 * 4);                     // 1.6 MB
  float* adst = (float*)alloc((size_t)NN * 4 * 4);                     // 1.6 MB
  int* es = (int*)alloc((size_t)ETOT * 4 + 128);                       // 6.8 MB + slack
  int* offs = (int*)alloc((size_t)(NN + 1) * 4);
  int* tmpb = (int*)alloc((size_t)EE * 4);                             // 6.4 MB
  int* H = (int*)alloc((size_t)512 * NBUK * 4);                        // 1 MB
  int* R = (int*)alloc((size_t)NBUK * 512 * 4);                        // 1 MB
  int* T = (int*)alloc((size_t)NBUK * 4);
  int* BaseTmp = (int*)alloc((size_t)(NBUK + 1) * 4);
  int* Base = (int*)alloc((size_t)(NBUK + 1) * 4);
  int* sync = (int*)alloc(64);

  hipMemsetAsync(sync, 0, 16, stream);
  k_mega<<<CB + GB, 256, 0, stream>>>(x, W, att_src, att_dst, ei, xwb, asrc, adst,
                                      H, R, T, BaseTmp, Base, tmpb, es, offs, sync);
  k_agg<<<NN / 4, 256, 0, stream>>>(xwb, asrc, adst, offs, es, bias, gamma, beta, out);
}

// Round 9
// 249.236 us; speedup vs baseline: 2.5424x; 2.5424x over previous
//
#include <hip/hip_runtime.h>
#include <math.h>

#define NN 100000
#define EE 1600000
#define ETOT (EE + NN)
#define NBUK 512
#define NPB 196        // nodes per bucket (512*196 >= NN)
#define CHUNK 3125     // 512*3125 == EE
#define CAP 6144       // LDS stage capacity per bucket (mean ~3332, +50 sigma)
#define GB 1563        // gemm blocks: ceil(NN/64)

typedef __attribute__((ext_vector_type(8))) short bf16x8;
typedef __attribute__((ext_vector_type(4))) float f32x4;

__device__ __forceinline__ unsigned short f2bf(float f) {
  unsigned int u = __float_as_uint(f);
  u = u + 0x7fffu + ((u >> 16) & 1u);  // RNE
  return (unsigned short)(u >> 16);
}

__device__ __forceinline__ float lrelu_exp(float e) {
  e = (e > 0.f) ? e : 0.2f * e;
  return __expf(e);
}

// Fused dispatch: blocks [0,GB) = MFMA bf16 GEMM + fused logits;
// blocks [GB, GB+NBUK) = P1 histogram + per-chunk bucket scan Sc (overlapped).
__global__ __launch_bounds__(256) void k_gemm(const float* __restrict__ x,
                                              const float* __restrict__ W,
                                              const float* __restrict__ att_src,
                                              const float* __restrict__ att_dst,
                                              const int* __restrict__ ei,
                                              unsigned short* __restrict__ xwb,
                                              float* __restrict__ asrc,
                                              float* __restrict__ adst,
                                              int* __restrict__ H,
                                              int* __restrict__ Sc) {
  __shared__ __align__(16) unsigned short lds[17408];  // GEMM: Wt[128][136]; p1: scan scratch
  __shared__ float satt[256];
  __shared__ int hh[NBUK];
  int tid = threadIdx.x;

  if (blockIdx.x >= GB) {
    // ---- P1 role: per-(chunk,bucket) histogram + within-chunk exclusive scan ----
    int j = blockIdx.x - GB;
    for (int i = tid; i < NBUK; i += 256) hh[i] = 0;
    __syncthreads();
    int e0 = j * CHUNK;
    for (int e = e0 + tid; e < e0 + CHUNK; e += 256) {
      int d = ei[(size_t)EE + e];
      atomicAdd(&hh[d / NPB], 1);
    }
    __syncthreads();
    for (int i = tid; i < NBUK; i += 256) H[j * NBUK + i] = hh[i];
    // exclusive scan of hh[0..511] (two 256-halves) -> Sc[j][b]
    int* s = (int*)lds;
    int va = hh[tid], vb = hh[tid + 256];
    s[tid] = va;
    __syncthreads();
    for (int off = 1; off < 256; off <<= 1) {
      int tmp = (tid >= off) ? s[tid - off] : 0;
      __syncthreads();
      s[tid] += tmp;
      __syncthreads();
    }
    int Sa = s[tid], SaT = s[255];
    __syncthreads();
    s[tid] = vb;
    __syncthreads();
    for (int off = 1; off < 256; off <<= 1) {
      int tmp = (tid >= off) ? s[tid - off] : 0;
      __syncthreads();
      s[tid] += tmp;
      __syncthreads();
    }
    Sc[j * 512 + tid] = Sa - va;
    Sc[j * 512 + 256 + tid] = SaT + s[tid] - vb;
    return;
  }

  // ---- GEMM role (unchanged) ----
  for (int i = tid; i < 16384; i += 256) {
    int k = i >> 7, n = i & 127;
    lds[n * 136 + k] = f2bf(W[i]);
  }
  if (tid < 128) satt[tid] = att_src[tid];
  else satt[tid] = att_dst[tid - 128];
  __syncthreads();

  int wv = tid >> 6, lane = tid & 63;
  int m = lane & 15, q = lane >> 4;
  int r = blockIdx.x * 64 + wv * 16 + m;
  bool rok = (r < NN);

  bf16x8 af[4];
#pragma unroll
  for (int kt = 0; kt < 4; kt++) {
    float4 v0 = make_float4(0.f, 0.f, 0.f, 0.f), v1 = v0;
    if (rok) {
      v0 = ((const float4*)x)[(size_t)r * 32 + kt * 8 + q * 2];
      v1 = ((const float4*)x)[(size_t)r * 32 + kt * 8 + q * 2 + 1];
    }
    af[kt][0] = (short)f2bf(v0.x); af[kt][1] = (short)f2bf(v0.y);
    af[kt][2] = (short)f2bf(v0.z); af[kt][3] = (short)f2bf(v0.w);
    af[kt][4] = (short)f2bf(v1.x); af[kt][5] = (short)f2bf(v1.y);
    af[kt][6] = (short)f2bf(v1.z); af[kt][7] = (short)f2bf(v1.w);
  }

  f32x4 acc[8];
#pragma unroll
  for (int nt = 0; nt < 8; nt++) acc[nt] = (f32x4){0.f, 0.f, 0.f, 0.f};

#pragma unroll
  for (int nt = 0; nt < 8; nt++) {
#pragma unroll
    for (int kt = 0; kt < 4; kt++) {
      bf16x8 bf = *((const bf16x8*)&lds[(nt * 16 + m) * 136 + kt * 32 + q * 8]);
      acc[nt] = __builtin_amdgcn_mfma_f32_16x16x32_bf16(af[kt], bf, acc[nt], 0, 0, 0);
    }
  }

  __syncthreads();  // reuse LDS as output stage
#pragma unroll
  for (int nt = 0; nt < 8; nt++)
#pragma unroll
    for (int rg = 0; rg < 4; rg++)
      lds[(wv * 16 + q * 4 + rg) * 128 + nt * 16 + m] = f2bf(acc[nt][rg]);
  __syncthreads();

  size_t base = (size_t)blockIdx.x * 16384;
  const size_t lim = (size_t)NN * 256;
  for (int i = tid; i < 1024; i += 256) {
    size_t off = base + (size_t)i * 16;
    if (off < lim) *((uint4*)((char*)xwb + off)) = ((const uint4*)lds)[i];
  }

  int row = tid >> 2, h = tid & 3;
  int node = blockIdx.x * 64 + row;
  if (node < NN) {
    float ss = 0.f, sd = 0.f;
#pragma unroll
    for (int cq = 0; cq < 4; cq++) {
      uint4 u = *((const uint4*)&lds[row * 128 + h * 32 + cq * 8]);
      int cb = h * 32 + cq * 8;
      float f0 = __uint_as_float(u.x << 16), f1 = __uint_as_float(u.x & 0xffff0000u);
      float f2 = __uint_as_float(u.y << 16), f3 = __uint_as_float(u.y & 0xffff0000u);
      float f4 = __uint_as_float(u.z << 16), f5 = __uint_as_float(u.z & 0xffff0000u);
      float f6 = __uint_as_float(u.w << 16), f7 = __uint_as_float(u.w & 0xffff0000u);
      ss += f0 * satt[cb] + f1 * satt[cb + 1] + f2 * satt[cb + 2] + f3 * satt[cb + 3] +
            f4 * satt[cb + 4] + f5 * satt[cb + 5] + f6 * satt[cb + 6] + f7 * satt[cb + 7];
      sd += f0 * satt[128 + cb] + f1 * satt[128 + cb + 1] + f2 * satt[128 + cb + 2] +
            f3 * satt[128 + cb + 3] + f4 * satt[128 + cb + 4] + f5 * satt[128 + cb + 5] +
            f6 * satt[128 + cb + 6] + f7 * satt[128 + cb + 7];
    }
    asrc[(size_t)node * 4 + h] = ss;
    adst[(size_t)node * 4 + h] = sd;
  }
}

// S1: per-bucket exclusive scan over chunks. R[bucket][chunk], totals T[bucket].
__global__ __launch_bounds__(512) void k_s1(const int* __restrict__ H,
                                            int* __restrict__ R, int* __restrict__ T) {
  __shared__ int s[512];
  int b = blockIdx.x, t = threadIdx.x;
  int v = H[t * NBUK + b];
  s[t] = v;
  __syncthreads();
  for (int off = 1; off < 512; off <<= 1) {
    int tmp = (t >= off) ? s[t - off] : 0;
    __syncthreads();
    s[t] += tmp;
    __syncthreads();
  }
  R[b * 512 + t] = s[t] - v;
  if (t == 511) T[b] = s[511];
}

// S2: bucket bases. Base = scan(T + nodecount(bucket)).
__global__ __launch_bounds__(512) void k_s2(const int* __restrict__ T,
                                            int* __restrict__ Base) {
  __shared__ int s2[512];
  int t = threadIdx.x;
  int v = T[t];
  int ncnt = NN - t * NPB;
  ncnt = (ncnt < 0) ? 0 : ((ncnt > NPB) ? NPB : ncnt);
  int w = v + ncnt;
  s2[t] = w;
  __syncthreads();
  for (int off = 1; off < 512; off <<= 1) {
    int tb = (t >= off) ? s2[t - off] : 0;
    __syncthreads();
    s2[t] += tb;
    __syncthreads();
  }
  Base[t] = s2[t] - w;
}

// P3: chunk-major staging. Block j sorts its 3125 edges by bucket in LDS
// (cursors from Sc[j][*]), then writes its contiguous tmpb segment COALESCED —
// no scattered-run global writes, no cross-XCD line ping-pong.
__global__ __launch_bounds__(256) void k_p3(const int* __restrict__ ei,
                                            const int* __restrict__ Sc,
                                            int* __restrict__ tmpb) {
  __shared__ int cur[NBUK];
  __shared__ int stage2[CHUNK];
  int j = blockIdx.x, t = threadIdx.x;
  for (int b = t; b < NBUK; b += 256) cur[b] = Sc[j * 512 + b];
  __syncthreads();
  int e0 = j * CHUNK;
  for (int e = e0 + t; e < e0 + CHUNK; e += 256) {
    int sv = ei[e];
    int dv = ei[(size_t)EE + e];
    int b = dv / NPB;
    int li = dv - b * NPB;
    int pos = atomicAdd(&cur[b], 1);
    stage2[pos] = (li << 17) | sv;  // pos < CHUNK by construction
  }
  __syncthreads();
  for (int i = t; i < CHUNK; i += 256) tmpb[(size_t)j * CHUNK + i] = stage2[i];
}

// P4: bucket b gathers its 512 runs (deterministic bases R[b][j], lens H[j][b],
// in-chunk starts Sc[j][b]) into LDS raw[] in ONE global pass, counts per-node,
// scans, scatters raw->stage in LDS, writes es coalesced.
__global__ __launch_bounds__(256) void k_p4(const int* __restrict__ tmpb,
                                            const int* __restrict__ H,
                                            const int* __restrict__ R,
                                            const int* __restrict__ T,
                                            const int* __restrict__ Sc,
                                            const int* __restrict__ Base,
                                            int* __restrict__ es, int* __restrict__ offs) {
  __shared__ int raw[CAP];
  __shared__ int stage[CAP];
  __shared__ int cnt[256];
  __shared__ int curn[NPB];
  int b = blockIdx.x, t = threadIdx.x;
  if (b == 0 && t == 0) offs[NN] = ETOT;
  int n0 = b * NPB;
  int nloc = NN - n0;
  if (nloc <= 0) return;
  if (nloc > NPB) nloc = NPB;
  int total = T[b];
  int bs = Base[b];
  cnt[t] = (t < nloc) ? 1 : 0;  // self-loop pre-counted
  __syncthreads();
  // gather runs + per-node count (single global pass over this bucket's edges)
  for (int jj = t; jj < 512; jj += 256) {
    int st = Sc[jj * 512 + b];
    int ln = H[jj * NBUK + b];
    int rb = R[b * 512 + jj];
    const int* src = tmpb + (size_t)jj * CHUNK + st;
    for (int k = 0; k < ln; k++) {
      int w = src[k];
      int p = rb + k;
      if (p < CAP) raw[p] = w;
      atomicAdd(&cnt[w >> 17], 1);
    }
  }
  __syncthreads();
  int v = cnt[t];
  __syncthreads();
  for (int off = 1; off < 256; off <<= 1) {
    int tmp = (t >= off) ? cnt[t - off] : 0;
    __syncthreads();
    cnt[t] += tmp;
    __syncthreads();
  }
  int excl = cnt[t] - v;
  if (t < nloc) {
    offs[n0 + t] = bs + excl;
    curn[t] = excl + 1;
    if (excl < CAP) stage[excl] = n0 + t;  // self-loop src first
  }
  __syncthreads();
  int tl = (total < CAP) ? total : CAP;
  for (int e = t; e < tl; e += 256) {
    int u = raw[e];
    int pos = atomicAdd(&curn[u >> 17], 1);
    if (pos < CAP) stage[pos] = u & 0x1FFFF;
  }
  __syncthreads();
  int btot = total + nloc;
  if (btot > CAP) btot = CAP;
  for (int i = t; i < btot; i += 256) es[bs + i] = stage[i];
}

// one wave per destination node (byte-identical to round 7).
__global__ __launch_bounds__(256) void k_agg(const unsigned short* __restrict__ xwb,
                                             const float* __restrict__ asrc,
                                             const float* __restrict__ adst,
                                             const int* __restrict__ offs,
                                             const int* __restrict__ es,
                                             const float* __restrict__ bias,
                                             const float* __restrict__ gamma,
                                             const float* __restrict__ beta,
                                             float* __restrict__ out) {
  int lane = threadIdx.x & 63;
  int node = blockIdx.x * 4 + (threadIdx.x >> 6);
  int off0 = offs[node];
  int d = offs[node + 1] - off0;
  int h = lane >> 4;
  int he = lane & 3;
  int sel = lane >> 3;
  int c = lane * 2;

  float4 ad4 = *((const float4*)(adst + (size_t)node * 4));
  float ade = (he & 2) ? ((he & 1) ? ad4.w : ad4.z) : ((he & 1) ? ad4.y : ad4.x);

  const unsigned* xp = (const unsigned*)xwb + lane;
  const int* ep = es + off0;
  float ax0 = 0.f, ay0 = 0.f, ax1 = 0.f, ay1 = 0.f;
  float wsum = 0.f;

  int nb = (d + 7) >> 3;
  int4 sa = *((const int4*)(ep));
  int4 sb = *((const int4*)(ep + 4));

  for (int b = 0; b < nb; ++b) {
    int4 na = *((const int4*)(ep + (b + 1) * 8));
    int4 nbv = *((const int4*)(ep + (b + 1) * 8 + 4));

    int base = b * 8;
    int s0 = sa.x, s1 = sa.y, s2 = sa.z, s3 = sa.w;
    int s4 = sb.x, s5 = sb.y, s6 = sb.z, s7 = sb.w;
    bool full = (base + 8 <= d);
    if (!full) {
      s0 = (base + 0 < d) ? s0 : 0; s1 = (base + 1 < d) ? s1 : 0;
      s2 = (base + 2 < d) ? s2 : 0; s3 = (base + 3 < d) ? s3 : 0;
      s4 = (base + 4 < d) ? s4 : 0; s5 = (base + 5 < d) ? s5 : 0;
      s6 = (base + 6 < d) ? s6 : 0; s7 = (base + 7 < d) ? s7 : 0;
    }
    int t0 = (sel & 1) ? s1 : s0;
    int t1 = (sel & 1) ? s3 : s2;
    int t2 = (sel & 1) ? s5 : s4;
    int t3 = (sel & 1) ? s7 : s6;
    int p0 = (sel & 2) ? t1 : t0;
    int p1 = (sel & 2) ? t3 : t2;
    int se = (sel & 4) ? p1 : p0;
    float av = asrc[(size_t)(unsigned)se * 4u + (unsigned)he];

    unsigned u0 = xp[(unsigned)s0 * 64u];
    unsigned u1 = xp[(unsigned)s1 * 64u];
    unsigned u2 = xp[(unsigned)s2 * 64u];
    unsigned u3 = xp[(unsigned)s3 * 64u];
    unsigned u4 = xp[(unsigned)s4 * 64u];
    unsigned u5 = xp[(unsigned)s5 * 64u];
    unsigned u6 = xp[(unsigned)s6 * 64u];
    unsigned u7 = xp[(unsigned)s7 * 64u];

    float wl = lrelu_exp(av + ade);
    float w0 = __shfl(wl, 0 * 8 + h);
    float w1 = __shfl(wl, 1 * 8 + h);
    float w2 = __shfl(wl, 2 * 8 + h);
    float w3 = __shfl(wl, 3 * 8 + h);
    float w4 = __shfl(wl, 4 * 8 + h);
    float w5 = __shfl(wl, 5 * 8 + h);
    float w6 = __shfl(wl, 6 * 8 + h);
    float w7 = __shfl(wl, 7 * 8 + h);
    if (!full) {
      w0 = (base + 0 < d) ? w0 : 0.f; w1 = (base + 1 < d) ? w1 : 0.f;
      w2 = (base + 2 < d) ? w2 : 0.f; w3 = (base + 3 < d) ? w3 : 0.f;
      w4 = (base + 4 < d) ? w4 : 0.f; w5 = (base + 5 < d) ? w5 : 0.f;
      w6 = (base + 6 < d) ? w6 : 0.f; w7 = (base + 7 < d) ? w7 : 0.f;
    }
    wsum += ((w0 + w1) + (w2 + w3)) + ((w4 + w5) + (w6 + w7));
    ax0 = fmaf(w0, __uint_as_float(u0 << 16), ax0);
    ay0 = fmaf(w0, __uint_as_float(u0 & 0xffff0000u), ay0);
    ax1 = fmaf(w1, __uint_as_float(u1 << 16), ax1);
    ay1 = fmaf(w1, __uint_as_float(u1 & 0xffff0000u), ay1);
    ax0 = fmaf(w2, __uint_as_float(u2 << 16), ax0);
    ay0 = fmaf(w2, __uint_as_float(u2 & 0xffff0000u), ay0);
    ax1 = fmaf(w3, __uint_as_float(u3 << 16), ax1);
    ay1 = fmaf(w3, __uint_as_float(u3 & 0xffff0000u), ay1);
    ax0 = fmaf(w4, __uint_as_float(u4 << 16), ax0);
    ay0 = fmaf(w4, __uint_as_float(u4 & 0xffff0000u), ay0);
    ax1 = fmaf(w5, __uint_as_float(u5 << 16), ax1);
    ay1 = fmaf(w5, __uint_as_float(u5 & 0xffff0000u), ay1);
    ax0 = fmaf(w6, __uint_as_float(u6 << 16), ax0);
    ay0 = fmaf(w6, __uint_as_float(u6 & 0xffff0000u), ay0);
    ax1 = fmaf(w7, __uint_as_float(u7 << 16), ax1);
    ay1 = fmaf(w7, __uint_as_float(u7 & 0xffff0000u), ay1);

    sa = na; sb = nbv;
  }

  float accx = ax0 + ax1, accy = ay0 + ay1;
  float rn = 1.f / (wsum + 1e-16f);

  float vx = accx * rn + bias[c];
  float vy = accy * rn + bias[c + 1];
  float sum = vx + vy, sq = vx * vx + vy * vy;
#pragma unroll
  for (int o = 32; o; o >>= 1) {
    sum += __shfl_xor(sum, o);
    sq += __shfl_xor(sq, o);
  }
  float mean = sum * (1.f / 128.f);
  float var = sq * (1.f / 128.f) - mean * mean;
  float rs = rsqrtf(var + 1e-5f);
  float o0 = gamma[c] * (vx - mean) * rs + beta[c];
  float o1 = gamma[c + 1] * (vy - mean) * rs + beta[c + 1];
  float2 ov; ov.x = o0; ov.y = o1;
  *((float2*)(out + (size_t)node * 128 + c)) = ov;
}

extern "C" void kernel_launch(void* const* d_in, const int* in_sizes, int n_in,
                              void* d_out, int out_size, void* d_ws, size_t ws_size,
                              hipStream_t stream) {
  const float* x = (const float*)d_in[0];
  const int* ei = (const int*)d_in[1];  // int32 per harness contract
  const float* W = (const float*)d_in[3];
  const float* att_src = (const float*)d_in[4];
  const float* att_dst = (const float*)d_in[5];
  const float* bias = (const float*)d_in[6];
  const float* gamma = (const float*)d_in[7];
  const float* beta = (const float*)d_in[8];
  float* out = (float*)d_out;

  char* p = (char*)d_ws;
  auto alloc = [&](size_t bytes) -> char* {
    char* r = p;
    p += (bytes + 255) & ~(size_t)255;
    return r;
  };
  unsigned short* xwb = (unsigned short*)alloc((size_t)NN * 128 * 2);  // 25.6 MB
  float* asrc = (float*)alloc((size_t)NN * 4 * 4);                     // 1.6 MB
  float* adst = (float*)alloc((size_t)NN * 4 * 4);                     // 1.6 MB
  int* es = (int*)alloc((size_t)ETOT * 4 + 128);                       // 6.8 MB + slack
  int* offs = (int*)alloc((size_t)(NN + 1) * 4);
  int* tmpb = (int*)alloc((size_t)EE * 4);                             // 6.4 MB, chunk-major
  int* H = (int*)alloc((size_t)512 * NBUK * 4);                        // 1 MB
  int* Sc = (int*)alloc((size_t)512 * NBUK * 4);                       // 1 MB
  int* R = (int*)alloc((size_t)NBUK * 512 * 4);                        // 1 MB
  int* T = (int*)alloc((size_t)NBUK * 4);
  int* Base = (int*)alloc((size_t)(NBUK + 1) * 4);

  k_gemm<<<GB + NBUK, 256, 0, stream>>>(x, W, att_src, att_dst, ei, xwb, asrc, adst, H, Sc);
  k_s1<<<NBUK, 512, 0, stream>>>(H, R, T);
  k_s2<<<1, 512, 0, stream>>>(T, Base);
  k_p3<<<512, 256, 0, stream>>>(ei, Sc, tmpb);
  k_p4<<<NBUK, 256, 0, stream>>>(tmpb, H, R, T, Sc, Base, es, offs);
  k_agg<<<NN / 4, 256, 0, stream>>>(xwb, asrc, adst, offs, es, bias, gamma, beta, out);
}

// Round 11
// 243.861 us; speedup vs baseline: 2.5984x; 1.0220x over previous
//
#include <hip/hip_runtime.h>
#include <math.h>

#define NN 100000
#define EE 1600000
#define ETOT (EE + NN)
#define NBUK 512
#define NPB 196        // nodes per bucket (512*196 >= NN)
#define CHUNK 3125     // 512*3125 == EE
#define CAP 6144       // LDS stage capacity per bucket (mean ~3332, +50 sigma)
#define GB 1563        // gemm blocks: ceil(NN/64)

typedef __attribute__((ext_vector_type(8))) short bf16x8;
typedef __attribute__((ext_vector_type(4))) float f32x4;

__device__ __forceinline__ unsigned short f2bf(float f) {
  unsigned int u = __float_as_uint(f);
  u = u + 0x7fffu + ((u >> 16) & 1u);  // RNE
  return (unsigned short)(u >> 16);
}

__device__ __forceinline__ float lrelu_exp(float e) {
  e = (e > 0.f) ? e : 0.2f * e;
  return __expf(e);
}

// Fused dispatch: blocks [0,GB) = MFMA bf16 GEMM + fused logits;
// blocks [GB, GB+NBUK) = P1 histogram + per-chunk bucket scan Sc (overlapped).
__global__ __launch_bounds__(256) void k_front(const float* __restrict__ x,
                                               const float* __restrict__ W,
                                               const float* __restrict__ att_src,
                                               const float* __restrict__ att_dst,
                                               const int* __restrict__ ei,
                                               unsigned short* __restrict__ xwb,
                                               float* __restrict__ asrc,
                                               float* __restrict__ adst,
                                               int* __restrict__ H,
                                               int* __restrict__ Sc) {
  __shared__ __align__(16) unsigned short lds[17408];  // GEMM: Wt[128][136]; p1: scan scratch
  __shared__ float satt[256];
  __shared__ int hh[NBUK];
  int tid = threadIdx.x;

  if (blockIdx.x >= GB) {
    // ---- P1 role: per-(chunk,bucket) histogram + within-chunk exclusive scan ----
    int j = blockIdx.x - GB;
    for (int i = tid; i < NBUK; i += 256) hh[i] = 0;
    __syncthreads();
    int e0 = j * CHUNK;
    for (int e = e0 + tid; e < e0 + CHUNK; e += 256) {
      int d = ei[(size_t)EE + e];
      atomicAdd(&hh[d / NPB], 1);
    }
    __syncthreads();
    for (int i = tid; i < NBUK; i += 256) H[j * NBUK + i] = hh[i];
    // exclusive scan of hh[0..511] (two 256-halves) -> Sc[j][b]
    int* s = (int*)lds;
    int va = hh[tid], vb = hh[tid + 256];
    s[tid] = va;
    __syncthreads();
    for (int off = 1; off < 256; off <<= 1) {
      int tmp = (tid >= off) ? s[tid - off] : 0;
      __syncthreads();
      s[tid] += tmp;
      __syncthreads();
    }
    int Sa = s[tid], SaT = s[255];
    __syncthreads();
    s[tid] = vb;
    __syncthreads();
    for (int off = 1; off < 256; off <<= 1) {
      int tmp = (tid >= off) ? s[tid - off] : 0;
      __syncthreads();
      s[tid] += tmp;
      __syncthreads();
    }
    Sc[j * 512 + tid] = Sa - va;
    Sc[j * 512 + 256 + tid] = SaT + s[tid] - vb;
    return;
  }

  // ---- GEMM role (unchanged) ----
  for (int i = tid; i < 16384; i += 256) {
    int k = i >> 7, n = i & 127;
    lds[n * 136 + k] = f2bf(W[i]);
  }
  if (tid < 128) satt[tid] = att_src[tid];
  else satt[tid] = att_dst[tid - 128];
  __syncthreads();

  int wv = tid >> 6, lane = tid & 63;
  int m = lane & 15, q = lane >> 4;
  int r = blockIdx.x * 64 + wv * 16 + m;
  bool rok = (r < NN);

  bf16x8 af[4];
#pragma unroll
  for (int kt = 0; kt < 4; kt++) {
    float4 v0 = make_float4(0.f, 0.f, 0.f, 0.f), v1 = v0;
    if (rok) {
      v0 = ((const float4*)x)[(size_t)r * 32 + kt * 8 + q * 2];
      v1 = ((const float4*)x)[(size_t)r * 32 + kt * 8 + q * 2 + 1];
    }
    af[kt][0] = (short)f2bf(v0.x); af[kt][1] = (short)f2bf(v0.y);
    af[kt][2] = (short)f2bf(v0.z); af[kt][3] = (short)f2bf(v0.w);
    af[kt][4] = (short)f2bf(v1.x); af[kt][5] = (short)f2bf(v1.y);
    af[kt][6] = (short)f2bf(v1.z); af[kt][7] = (short)f2bf(v1.w);
  }

  f32x4 acc[8];
#pragma unroll
  for (int nt = 0; nt < 8; nt++) acc[nt] = (f32x4){0.f, 0.f, 0.f, 0.f};

#pragma unroll
  for (int nt = 0; nt < 8; nt++) {
#pragma unroll
    for (int kt = 0; kt < 4; kt++) {
      bf16x8 bf = *((const bf16x8*)&lds[(nt * 16 + m) * 136 + kt * 32 + q * 8]);
      acc[nt] = __builtin_amdgcn_mfma_f32_16x16x32_bf16(af[kt], bf, acc[nt], 0, 0, 0);
    }
  }

  __syncthreads();  // reuse LDS as output stage
#pragma unroll
  for (int nt = 0; nt < 8; nt++)
#pragma unroll
    for (int rg = 0; rg < 4; rg++)
      lds[(wv * 16 + q * 4 + rg) * 128 + nt * 16 + m] = f2bf(acc[nt][rg]);
  __syncthreads();

  size_t base = (size_t)blockIdx.x * 16384;
  const size_t lim = (size_t)NN * 256;
  for (int i = tid; i < 1024; i += 256) {
    size_t off = base + (size_t)i * 16;
    if (off < lim) *((uint4*)((char*)xwb + off)) = ((const uint4*)lds)[i];
  }

  int row = tid >> 2, h = tid & 3;
  int node = blockIdx.x * 64 + row;
  if (node < NN) {
    float ss = 0.f, sd = 0.f;
#pragma unroll
    for (int cq = 0; cq < 4; cq++) {
      uint4 u = *((const uint4*)&lds[row * 128 + h * 32 + cq * 8]);
      int cb = h * 32 + cq * 8;
      float f0 = __uint_as_float(u.x << 16), f1 = __uint_as_float(u.x & 0xffff0000u);
      float f2 = __uint_as_float(u.y << 16), f3 = __uint_as_float(u.y & 0xffff0000u);
      float f4 = __uint_as_float(u.z << 16), f5 = __uint_as_float(u.z & 0xffff0000u);
      float f6 = __uint_as_float(u.w << 16), f7 = __uint_as_float(u.w & 0xffff0000u);
      ss += f0 * satt[cb] + f1 * satt[cb + 1] + f2 * satt[cb + 2] + f3 * satt[cb + 3] +
            f4 * satt[cb + 4] + f5 * satt[cb + 5] + f6 * satt[cb + 6] + f7 * satt[cb + 7];
      sd += f0 * satt[128 + cb] + f1 * satt[128 + cb + 1] + f2 * satt[128 + cb + 2] +
            f3 * satt[128 + cb + 3] + f4 * satt[128 + cb + 4] + f5 * satt[128 + cb + 5] +
            f6 * satt[128 + cb + 6] + f7 * satt[128 + cb + 7];
    }
    asrc[(size_t)node * 4 + h] = ss;
    adst[(size_t)node * 4 + h] = sd;
  }
}

// Fused S1 || P3 (independent stages): blocks [0,NBUK) = S1 per-bucket scan over
// chunks (verified 256-thread two-half form); blocks [NBUK, 2*NBUK) = P3 chunk-major
// LDS sort + coalesced tmpb write. One dispatch, s1 hides under p3.
__global__ __launch_bounds__(256) void k_s1p3(const int* __restrict__ ei,
                                              const int* __restrict__ H,
                                              const int* __restrict__ Sc,
                                              int* __restrict__ R, int* __restrict__ T,
                                              int* __restrict__ tmpb) {
  __shared__ int sh[512 + CHUNK];  // s1: scan scratch; p3: cur[512] + stage2[3125]
  int t = threadIdx.x;

  if (blockIdx.x < NBUK) {
    // ---- S1 role: bucket b, exclusive scan of H[j][b] over j (2x256 halves) ----
    int b = blockIdx.x;
    int* s = sh;
    int va = H[t * NBUK + b];
    int vb = H[(t + 256) * NBUK + b];
    s[t] = va;
    __syncthreads();
    for (int off = 1; off < 256; off <<= 1) {
      int tmp = (t >= off) ? s[t - off] : 0;
      __syncthreads();
      s[t] += tmp;
      __syncthreads();
    }
    int Sa = s[t], SaT = s[255];
    __syncthreads();
    s[t] = vb;
    __syncthreads();
    for (int off = 1; off < 256; off <<= 1) {
      int tmp = (t >= off) ? s[t - off] : 0;
      __syncthreads();
      s[t] += tmp;
      __syncthreads();
    }
    R[b * 512 + t] = Sa - va;
    R[b * 512 + 256 + t] = SaT + s[t] - vb;
    if (t == 255) T[b] = SaT + s[255];
    return;
  }

  // ---- P3 role: chunk j — LDS bucket-sort, coalesced chunk-major tmpb write ----
  int j = blockIdx.x - NBUK;
  int* cur = sh;
  int* stage2 = sh + 512;
  for (int b2 = t; b2 < NBUK; b2 += 256) cur[b2] = Sc[j * 512 + b2];
  __syncthreads();
  int e0 = j * CHUNK;
  for (int e = e0 + t; e < e0 + CHUNK; e += 256) {
    int sv = ei[e];
    int dv = ei[(size_t)EE + e];
    int b2 = dv / NPB;
    int li = dv - b2 * NPB;
    int pos = atomicAdd(&cur[b2], 1);
    stage2[pos] = (li << 17) | sv;  // pos < CHUNK by construction
  }
  __syncthreads();
  for (int i = t; i < CHUNK; i += 256) tmpb[(size_t)j * CHUNK + i] = stage2[i];
}

// P4 (+inline S2): bucket b computes Base[b] = prefix-sum(T[0..b-1]) + b*NPB
// locally (analytic self-loop prefix), then gathers its 512 runs into LDS raw[]
// in one global pass, counts per-node, scans, scatters, writes es coalesced.
__global__ __launch_bounds__(256) void k_p4(const int* __restrict__ tmpb,
                                            const int* __restrict__ H,
                                            const int* __restrict__ R,
                                            const int* __restrict__ T,
                                            const int* __restrict__ Sc,
                                            int* __restrict__ es, int* __restrict__ offs) {
  __shared__ int raw[CAP];
  __shared__ int stage[CAP];
  __shared__ int cnt[256];
  __shared__ int curn[NPB];
  int b = blockIdx.x, t = threadIdx.x;
  if (b == 0 && t == 0) offs[NN] = ETOT;
  int n0 = b * NPB;
  int nloc = NN - n0;
  if (nloc <= 0) return;
  if (nloc > NPB) nloc = NPB;
  int total = T[b];
  // inline S2: block-local reduce of T[0..b-1]; self-loop prefix = n0 (n0 < NN here)
  int pacc = 0;
  for (int i = t; i < b; i += 256) pacc += T[i];
  cnt[t] = pacc;
  __syncthreads();
  for (int off = 128; off; off >>= 1) {
    if (t < off) cnt[t] += cnt[t + off];
    __syncthreads();
  }
  int bs = cnt[0] + n0;
  __syncthreads();
  cnt[t] = (t < nloc) ? 1 : 0;  // self-loop pre-counted
  __syncthreads();
  // gather runs + per-node count (single global pass over this bucket's edges)
  for (int jj = t; jj < 512; jj += 256) {
    int st = Sc[jj * 512 + b];
    int ln = H[jj * NBUK + b];
    int rb = R[b * 512 + jj];
    const int* src = tmpb + (size_t)jj * CHUNK + st;
    for (int k = 0; k < ln; k++) {
      int w = src[k];
      int p = rb + k;
      if (p < CAP) raw[p] = w;
      atomicAdd(&cnt[w >> 17], 1);
    }
  }
  __syncthreads();
  int v = cnt[t];
  __syncthreads();
  for (int off = 1; off < 256; off <<= 1) {
    int tmp = (t >= off) ? cnt[t - off] : 0;
    __syncthreads();
    cnt[t] += tmp;
    __syncthreads();
  }
  int excl = cnt[t] - v;
  if (t < nloc) {
    offs[n0 + t] = bs + excl;
    curn[t] = excl + 1;
    if (excl < CAP) stage[excl] = n0 + t;  // self-loop src first
  }
  __syncthreads();
  int tl = (total < CAP) ? total : CAP;
  for (int e = t; e < tl; e += 256) {
    int u = raw[e];
    int pos = atomicAdd(&curn[u >> 17], 1);
    if (pos < CAP) stage[pos] = u & 0x1FFFF;
  }
  __syncthreads();
  int btot = total + nloc;
  if (btot > CAP) btot = CAP;
  for (int i = t; i < btot; i += 256) es[bs + i] = stage[i];
}

// one wave per destination node (byte-identical to round 7/9).
__global__ __launch_bounds__(256) void k_agg(const unsigned short* __restrict__ xwb,
                                             const float* __restrict__ asrc,
                                             const float* __restrict__ adst,
                                             const int* __restrict__ offs,
                                             const int* __restrict__ es,
                                             const float* __restrict__ bias,
                                             const float* __restrict__ gamma,
                                             const float* __restrict__ beta,
                                             float* __restrict__ out) {
  int lane = threadIdx.x & 63;
  int node = blockIdx.x * 4 + (threadIdx.x >> 6);
  int off0 = offs[node];
  int d = offs[node + 1] - off0;
  int h = lane >> 4;
  int he = lane & 3;
  int sel = lane >> 3;
  int c = lane * 2;

  float4 ad4 = *((const float4*)(adst + (size_t)node * 4));
  float ade = (he & 2) ? ((he & 1) ? ad4.w : ad4.z) : ((he & 1) ? ad4.y : ad4.x);

  const unsigned* xp = (const unsigned*)xwb + lane;
  const int* ep = es + off0;
  float ax0 = 0.f, ay0 = 0.f, ax1 = 0.f, ay1 = 0.f;
  float wsum = 0.f;

  int nb = (d + 7) >> 3;
  int4 sa = *((const int4*)(ep));
  int4 sb = *((const int4*)(ep + 4));

  for (int b = 0; b < nb; ++b) {
    int4 na = *((const int4*)(ep + (b + 1) * 8));
    int4 nbv = *((const int4*)(ep + (b + 1) * 8 + 4));

    int base = b * 8;
    int s0 = sa.x, s1 = sa.y, s2 = sa.z, s3 = sa.w;
    int s4 = sb.x, s5 = sb.y, s6 = sb.z, s7 = sb.w;
    bool full = (base + 8 <= d);
    if (!full) {
      s0 = (base + 0 < d) ? s0 : 0; s1 = (base + 1 < d) ? s1 : 0;
      s2 = (base + 2 < d) ? s2 : 0; s3 = (base + 3 < d) ? s3 : 0;
      s4 = (base + 4 < d) ? s4 : 0; s5 = (base + 5 < d) ? s5 : 0;
      s6 = (base + 6 < d) ? s6 : 0; s7 = (base + 7 < d) ? s7 : 0;
    }
    int t0 = (sel & 1) ? s1 : s0;
    int t1 = (sel & 1) ? s3 : s2;
    int t2 = (sel & 1) ? s5 : s4;
    int t3 = (sel & 1) ? s7 : s6;
    int p0 = (sel & 2) ? t1 : t0;
    int p1 = (sel & 2) ? t3 : t2;
    int se = (sel & 4) ? p1 : p0;
    float av = asrc[(size_t)(unsigned)se * 4u + (unsigned)he];

    unsigned u0 = xp[(unsigned)s0 * 64u];
    unsigned u1 = xp[(unsigned)s1 * 64u];
    unsigned u2 = xp[(unsigned)s2 * 64u];
    unsigned u3 = xp[(unsigned)s3 * 64u];
    unsigned u4 = xp[(unsigned)s4 * 64u];
    unsigned u5 = xp[(unsigned)s5 * 64u];
    unsigned u6 = xp[(unsigned)s6 * 64u];
    unsigned u7 = xp[(unsigned)s7 * 64u];

    float wl = lrelu_exp(av + ade);
    float w0 = __shfl(wl, 0 * 8 + h);
    float w1 = __shfl(wl, 1 * 8 + h);
    float w2 = __shfl(wl, 2 * 8 + h);
    float w3 = __shfl(wl, 3 * 8 + h);
    float w4 = __shfl(wl, 4 * 8 + h);
    float w5 = __shfl(wl, 5 * 8 + h);
    float w6 = __shfl(wl, 6 * 8 + h);
    float w7 = __shfl(wl, 7 * 8 + h);
    if (!full) {
      w0 = (base + 0 < d) ? w0 : 0.f; w1 = (base + 1 < d) ? w1 : 0.f;
      w2 = (base + 2 < d) ? w2 : 0.f; w3 = (base + 3 < d) ? w3 : 0.f;
      w4 = (base + 4 < d) ? w4 : 0.f; w5 = (base + 5 < d) ? w5 : 0.f;
      w6 = (base + 6 < d) ? w6 : 0.f; w7 = (base + 7 < d) ? w7 : 0.f;
    }
    wsum += ((w0 + w1) + (w2 + w3)) + ((w4 + w5) + (w6 + w7));
    ax0 = fmaf(w0, __uint_as_float(u0 << 16), ax0);
    ay0 = fmaf(w0, __uint_as_float(u0 & 0xffff0000u), ay0);
    ax1 = fmaf(w1, __uint_as_float(u1 << 16), ax1);
    ay1 = fmaf(w1, __uint_as_float(u1 & 0xffff0000u), ay1);
    ax0 = fmaf(w2, __uint_as_float(u2 << 16), ax0);
    ay0 = fmaf(w2, __uint_as_float(u2 & 0xffff0000u), ay0);
    ax1 = fmaf(w3, __uint_as_float(u3 << 16), ax1);
    ay1 = fmaf(w3, __uint_as_float(u3 & 0xffff0000u), ay1);
    ax0 = fmaf(w4, __uint_as_float(u4 << 16), ax0);
    ay0 = fmaf(w4, __uint_as_float(u4 & 0xffff0000u), ay0);
    ax1 = fmaf(w5, __uint_as_float(u5 << 16), ax1);
    ay1 = fmaf(w5, __uint_as_float(u5 & 0xffff0000u), ay1);
    ax0 = fmaf(w6, __uint_as_float(u6 << 16), ax0);
    ay0 = fmaf(w6, __uint_as_float(u6 & 0xffff0000u), ay0);
    ax1 = fmaf(w7, __uint_as_float(u7 << 16), ax1);
    ay1 = fmaf(w7, __uint_as_float(u7 & 0xffff0000u), ay1);

    sa = na; sb = nbv;
  }

  float accx = ax0 + ax1, accy = ay0 + ay1;
  float rn = 1.f / (wsum + 1e-16f);

  float vx = accx * rn + bias[c];
  float vy = accy * rn + bias[c + 1];
  float sum = vx + vy, sq = vx * vx + vy * vy;
#pragma unroll
  for (int o = 32; o; o >>= 1) {
    sum += __shfl_xor(sum, o);
    sq += __shfl_xor(sq, o);
  }
  float mean = sum * (1.f / 128.f);
  float var = sq * (1.f / 128.f) - mean * mean;
  float rs = rsqrtf(var + 1e-5f);
  float o0 = gamma[c] * (vx - mean) * rs + beta[c];
  float o1 = gamma[c + 1] * (vy - mean) * rs + beta[c + 1];
  float2 ov; ov.x = o0; ov.y = o1;
  *((float2*)(out + (size_t)node * 128 + c)) = ov;
}

extern "C" void kernel_launch(void* const* d_in, const int* in_sizes, int n_in,
                              void* d_out, int out_size, void* d_ws, size_t ws_size,
                              hipStream_t stream) {
  const float* x = (const float*)d_in[0];
  const int* ei = (const int*)d_in[1];  // int32 per harness contract
  const float* W = (const float*)d_in[3];
  const float* att_src = (const float*)d_in[4];
  const float* att_dst = (const float*)d_in[5];
  const float* bias = (const float*)d_in[6];
  const float* gamma = (const float*)d_in[7];
  const float* beta = (const float*)d_in[8];
  float* out = (float*)d_out;

  char* p = (char*)d_ws;
  auto alloc = [&](size_t bytes) -> char* {
    char* r = p;
    p += (bytes + 255) & ~(size_t)255;
    return r;
  };
  unsigned short* xwb = (unsigned short*)alloc((size_t)NN * 128 * 2);  // 25.6 MB
  float* asrc = (float*)alloc((size_t)NN * 4 * 4);                     // 1.6 MB
  float* adst = (float*)alloc((size_t)NN * 4 * 4);                     // 1.6 MB
  int* es = (int*)alloc((size_t)ETOT * 4 + 128);                       // 6.8 MB + slack
  int* offs = (int*)alloc((size_t)(NN + 1) * 4);
  int* tmpb = (int*)alloc((size_t)EE * 4);                             // 6.4 MB, chunk-major
  int* H = (int*)alloc((size_t)512 * NBUK * 4);                        // 1 MB
  int* Sc = (int*)alloc((size_t)512 * NBUK * 4);                       // 1 MB
  int* R = (int*)alloc((size_t)NBUK * 512 * 4);                        // 1 MB
  int* T = (int*)alloc((size_t)NBUK * 4);

  k_front<<<GB + NBUK, 256, 0, stream>>>(x, W, att_src, att_dst, ei, xwb, asrc, adst, H, Sc);
  k_s1p3<<<2 * NBUK, 256, 0, stream>>>(ei, H, Sc, R, T, tmpb);
  k_p4<<<NBUK, 256, 0, stream>>>(tmpb, H, R, T, Sc, es, offs);
  k_agg<<<NN / 4, 256, 0, stream>>>(xwb, asrc, adst, offs, es, bias, gamma, beta, out);
}